// Round 1
// baseline (629.092 us; speedup 1.0000x reference)
//
#include <hip/hip_runtime.h>

// LSTM: B=8192 independent sequences, T=512, H=32.
// One wave (64 threads) per 16 batches -> 512 blocks of 64.
// Recurrent matvec h@W_hh^T via mfma_f32_16x16x32_bf16 with hi/lo bf16 split
// (3 MFMAs) for fp32-equivalent precision. c-state in registers, h exchanged
// through LDS each step. x-projection and biases added in exact fp32.

#define TT 512
#define HH 32

typedef short bf16x8 __attribute__((ext_vector_type(8)));
typedef float f32x4 __attribute__((ext_vector_type(4)));

__device__ __forceinline__ short f2bf(float f) {
    unsigned u = __float_as_uint(f);
    u = (u + 0x7FFFu + ((u >> 16) & 1u)) >> 16;
    return (short)u;
}
__device__ __forceinline__ float bf2f(short s) {
    return __uint_as_float(((unsigned)(unsigned short)s) << 16);
}
__device__ __forceinline__ float fastrcp(float x) { return __builtin_amdgcn_rcpf(x); }
__device__ __forceinline__ float sigm(float x) {
    return fastrcp(1.f + __expf(-x));
}
__device__ __forceinline__ float tanhf_(float x) {
    float e = __expf(2.f * x);            // e -> inf => tanh -> 1; e -> 0 => -1
    return 1.f - 2.f * fastrcp(e + 1.f);
}

// Permuted k-order: LDS position p holds hidden unit u(p); applied identically
// to the A (h) layout and B (W_hh) fragments so the MFMA contraction is valid.
// p even -> u = p/2 ; p odd -> u = 16 + p/2. This makes each lane's two h
// outputs (units c, c+16) a contiguous float2 store.
__device__ __forceinline__ int unit_of_pos(int p) {
    return (p & 1) ? (16 + (p >> 1)) : (p >> 1);
}

__launch_bounds__(64)
__global__ void lstm_kernel(const float* __restrict__ x,
                            const float* __restrict__ W_ih,
                            const float* __restrict__ W_hh,
                            const float* __restrict__ b_ih,
                            const float* __restrict__ b_hh,
                            const float* __restrict__ W_fc,
                            const float* __restrict__ b_fc,
                            float* __restrict__ out) {
    __shared__ float hbuf[16 * 36];   // [batch][32 units, permuted] pad to 36

    const int lane = threadIdx.x;     // block = exactly one wave
    const int c    = lane & 15;       // MFMA n / m index
    const int q    = lane >> 4;       // quad
    const int k0   = q * 8;           // k-block base for A/B fragments
    const int base = blockIdx.x * 16; // first batch of this wave's group

    // ---- one-time: W_hh fragments (hi/lo bf16 split), W_ih + bias scalars ----
    bf16x8 wh[8], wl[8];
    float wih8[8], bb8[8];
    #pragma unroll
    for (int t8 = 0; t8 < 8; ++t8) {
        const int g = c + 16 * t8;    // gate row: t8=0,1->i ; 2,3->f ; 4,5->g ; 6,7->o
        #pragma unroll
        for (int j = 0; j < 8; ++j) {
            const int u = unit_of_pos(k0 + j);
            const float w = W_hh[g * HH + u];
            const short hi16 = f2bf(w);
            wh[t8][j] = hi16;
            wl[t8][j] = f2bf(w - bf2f(hi16));
        }
        wih8[t8] = W_ih[g];
        bb8[t8]  = b_ih[g] + b_hh[g];
    }

    // zero h buffer (h0 = 0)
    for (int i = lane; i < 16 * 36; i += 64) hbuf[i] = 0.f;

    float cs[8];                      // c-state: [r(4 batches)][2 units]
    #pragma unroll
    for (int i = 0; i < 8; ++i) cs[i] = 0.f;

    // prefetch x for t=0 (this lane's 4 batches: q*4 + r)
    float xn[4];
    #pragma unroll
    for (int r = 0; r < 4; ++r) xn[r] = x[(base + q * 4 + r) * TT + 0];

    __syncthreads();

    for (int t = 0; t < TT; ++t) {
        // ---- A fragments: read h (fp32) from LDS, split into hi/lo bf16 ----
        const float* hrow = &hbuf[c * 36 + k0];
        const float4 lo4 = *(const float4*)(hrow);
        const float4 hi4 = *(const float4*)(hrow + 4);
        const float hv8[8] = {lo4.x, lo4.y, lo4.z, lo4.w,
                              hi4.x, hi4.y, hi4.z, hi4.w};
        bf16x8 hh, hl;
        #pragma unroll
        for (int j = 0; j < 8; ++j) {
            const short a = f2bf(hv8[j]);
            hh[j] = a;
            hl[j] = f2bf(hv8[j] - bf2f(a));
        }

        // ---- gates = h @ W_hh^T  (fp32-equivalent via 3-term split) ----
        f32x4 acc[8];
        #pragma unroll
        for (int t8 = 0; t8 < 8; ++t8) {
            f32x4 z = {0.f, 0.f, 0.f, 0.f};
            z = __builtin_amdgcn_mfma_f32_16x16x32_bf16(hh, wl[t8], z, 0, 0, 0);
            z = __builtin_amdgcn_mfma_f32_16x16x32_bf16(hl, wh[t8], z, 0, 0, 0);
            z = __builtin_amdgcn_mfma_f32_16x16x32_bf16(hh, wh[t8], z, 0, 0, 0);
            acc[t8] = z;
        }

        // consume prefetched x, issue prefetch for t+1 (overlaps elementwise)
        float xc[4];
        #pragma unroll
        for (int r = 0; r < 4; ++r) xc[r] = xn[r];
        const int tn = (t + 1 < TT) ? (t + 1) : (TT - 1);
        #pragma unroll
        for (int r = 0; r < 4; ++r) xn[r] = x[(base + q * 4 + r) * TT + tn];

        // ---- elementwise LSTM cell update (fp32) ----
        // lane holds gates for batches q*4+r (r = acc reg idx) and units c, c+16
        float hvout[4][2];
        #pragma unroll
        for (int r = 0; r < 4; ++r) {
            #pragma unroll
            for (int ui = 0; ui < 2; ++ui) {
                const float pi = acc[0 + ui][r] + wih8[0 + ui] * xc[r] + bb8[0 + ui];
                const float pf = acc[2 + ui][r] + wih8[2 + ui] * xc[r] + bb8[2 + ui];
                const float pg = acc[4 + ui][r] + wih8[4 + ui] * xc[r] + bb8[4 + ui];
                const float po = acc[6 + ui][r] + wih8[6 + ui] * xc[r] + bb8[6 + ui];
                const float ig = sigm(pi);
                const float fg = sigm(pf);
                const float gg = tanhf_(pg);
                const float og = sigm(po);
                const float cn = fg * cs[r * 2 + ui] + ig * gg;
                cs[r * 2 + ui] = cn;
                hvout[r][ui] = og * tanhf_(cn);
            }
        }

        // ---- write h back to LDS (pair-permuted layout: units c,c+16 adjacent)
        #pragma unroll
        for (int r = 0; r < 4; ++r) {
            float2 v = make_float2(hvout[r][0], hvout[r][1]);
            *(float2*)&hbuf[(q * 4 + r) * 36 + 2 * c] = v;
        }
        __syncthreads();   // write(t) -> read(t+1) ordering (single-wave barrier)
    }

    // ---- head: out[b] = h_T @ W_fc^T + b_fc (h_T is in hbuf) ----
    if (lane < 16) {
        float s = b_fc[0];
        #pragma unroll
        for (int p = 0; p < 32; ++p) {
            s += hbuf[lane * 36 + p] * W_fc[unit_of_pos(p)];
        }
        out[base + lane] = s;
    }
}

extern "C" void kernel_launch(void* const* d_in, const int* in_sizes, int n_in,
                              void* d_out, int out_size, void* d_ws, size_t ws_size,
                              hipStream_t stream) {
    const float* x    = (const float*)d_in[0];
    const float* W_ih = (const float*)d_in[1];
    const float* W_hh = (const float*)d_in[2];
    const float* b_ih = (const float*)d_in[3];
    const float* b_hh = (const float*)d_in[4];
    const float* W_fc = (const float*)d_in[5];
    const float* b_fc = (const float*)d_in[6];
    float* out = (float*)d_out;

    const int B = 8192;
    lstm_kernel<<<B / 16, 64, 0, stream>>>(x, W_ih, W_hh, b_ih, b_hh,
                                           W_fc, b_fc, out);
}

// Round 2
// 371.171 us; speedup vs baseline: 1.6949x; 1.6949x over previous
//
#include <hip/hip_runtime.h>

// LSTM: B=8192, T=512, H=32.
// Block = 256 threads (4 waves) per 16-batch group; 512 blocks.
// Wave w computes gate w (2 MFMA n-tiles) for all 16 batches via
// mfma_f32_16x16x32_bf16 with hi/lo bf16 split (3 MFMAs per tile, arranged as
// two short dependency chains). Gates exchanged through LDS; elementwise cell
// update split 2 updates/thread. h stored to LDS as producer-split bf16 hi/lo
// pairs ready for direct b128 A-fragment reads. c-state in fp32 registers.

#define TT 512
#define HH 32

typedef short bf16x8 __attribute__((ext_vector_type(8)));
typedef float f32x4 __attribute__((ext_vector_type(4)));

__device__ __forceinline__ short f2bf(float f) {
    unsigned u = __float_as_uint(f);
    u = (u + 0x7FFFu + ((u >> 16) & 1u)) >> 16;
    return (short)u;
}
__device__ __forceinline__ float bf2f(short s) {
    return __uint_as_float(((unsigned)(unsigned short)s) << 16);
}
__device__ __forceinline__ float fastrcp(float x) { return __builtin_amdgcn_rcpf(x); }
__device__ __forceinline__ float sigm(float x) {
    return fastrcp(1.f + __expf(-x));
}
__device__ __forceinline__ float tanhf_(float x) {
    float e = __expf(2.f * x);            // e->inf => 1 ; e->0 => -1
    return 1.f - 2.f * fastrcp(e + 1.f);
}

// k-position permutation (applied identically to A and B fragments):
// p even -> unit p/2 ; p odd -> unit 16 + p/2. Makes each producer thread's
// two h outputs (units u, u+16) a contiguous pair at positions 2u, 2u+1.
__device__ __forceinline__ int unit_of_pos(int p) {
    return (p & 1) ? (16 + (p >> 1)) : (p >> 1);
}

#define GSTRIDE 132   // gbuf batch stride (floats): 128 + 4 pad -> 2-way banks
#define HSTRIDE 40    // h buf batch stride (shorts): 32 + 8 pad, keeps 16B align

__launch_bounds__(256, 2)
__global__ void lstm_kernel(const float* __restrict__ x,
                            const float* __restrict__ W_ih,
                            const float* __restrict__ W_hh,
                            const float* __restrict__ b_ih,
                            const float* __restrict__ b_hh,
                            const float* __restrict__ W_fc,
                            const float* __restrict__ b_fc,
                            float* __restrict__ out) {
    __shared__ float gbuf[16 * GSTRIDE];   // [batch][unit][gate 0..3]
    __shared__ short hhbuf[16 * HSTRIDE];  // h hi-bf16, [batch][pos]
    __shared__ short hlbuf[16 * HSTRIDE];  // h lo-bf16

    const int tid  = threadIdx.x;
    const int lane = tid & 63;
    const int w    = tid >> 6;        // wave id == gate id (0:i 1:f 2:g 3:o)
    const int c    = lane & 15;       // MFMA m/n index
    const int q    = lane >> 4;       // quad
    const int k0   = q * 8;           // k-block base
    const int base = blockIdx.x * 16;

    // ---- MFMA weights: gate rows 32w + 16*ui + c, hi/lo bf16 split ----
    bf16x8 wh[2], wl[2];
    #pragma unroll
    for (int ui = 0; ui < 2; ++ui) {
        const int g = 32 * w + 16 * ui + c;
        #pragma unroll
        for (int j = 0; j < 8; ++j) {
            const int u = unit_of_pos(k0 + j);
            const float wf = W_hh[g * HH + u];
            const short hi = f2bf(wf);
            wh[ui][j] = hi;
            wl[ui][j] = f2bf(wf - bf2f(hi));
        }
    }

    // ---- elementwise constants: thread (bb, uu) updates units uu, uu+16 ----
    const int bb = tid & 15;
    const int uu = (tid >> 4) & 15;
    float wih[2][4], bc[2][4];
    #pragma unroll
    for (int ui = 0; ui < 2; ++ui) {
        #pragma unroll
        for (int g = 0; g < 4; ++g) {
            const int row = g * 32 + uu + 16 * ui;
            wih[ui][g] = W_ih[row];
            bc[ui][g]  = b_ih[row] + b_hh[row];
        }
    }

    // ---- init h = 0 ----
    for (int i = tid; i < 16 * HSTRIDE; i += 256) { hhbuf[i] = 0; hlbuf[i] = 0; }

    float cs0 = 0.f, cs1 = 0.f;       // c-state for units uu, uu+16 of batch bb
    float xn = x[(base + bb) * TT + 0];

    __syncthreads();

    for (int t = 0; t < TT; ++t) {
        // ---- phase A: recurrent matvec (all 4 waves, own gate) ----
        const bf16x8 ahh = *(const bf16x8*)&hhbuf[c * HSTRIDE + k0];
        const bf16x8 ahl = *(const bf16x8*)&hlbuf[c * HSTRIDE + k0];

        f32x4 z1[2], z2[2];
        #pragma unroll
        for (int ui = 0; ui < 2; ++ui) {
            f32x4 zz = {0.f, 0.f, 0.f, 0.f};
            z1[ui] = __builtin_amdgcn_mfma_f32_16x16x32_bf16(ahh, wh[ui], zz, 0, 0, 0);
            f32x4 y = __builtin_amdgcn_mfma_f32_16x16x32_bf16(ahl, wh[ui], zz, 0, 0, 0);
            z2[ui] = __builtin_amdgcn_mfma_f32_16x16x32_bf16(ahh, wl[ui], y, 0, 0, 0);
        }
        // lane (c,q): D[row=q*4+r][col=c] = gate w, batch q*4+r, unit c+16ui
        #pragma unroll
        for (int ui = 0; ui < 2; ++ui) {
            #pragma unroll
            for (int r = 0; r < 4; ++r) {
                gbuf[(q * 4 + r) * GSTRIDE + (c + 16 * ui) * 4 + w] =
                    z1[ui][r] + z2[ui][r];
            }
        }
        __syncthreads();

        // ---- phase B: elementwise cell update (2 units per thread) ----
        const float4 gA = *(const float4*)&gbuf[bb * GSTRIDE + uu * 4];
        const float4 gB = *(const float4*)&gbuf[bb * GSTRIDE + (uu + 16) * 4];

        const float xc = xn;
        const int tn = (t + 1 < TT) ? (t + 1) : (TT - 1);
        xn = x[(base + bb) * TT + tn];

        // unit uu
        float pi = gA.x + wih[0][0] * xc + bc[0][0];
        float pf = gA.y + wih[0][1] * xc + bc[0][1];
        float pg = gA.z + wih[0][2] * xc + bc[0][2];
        float po = gA.w + wih[0][3] * xc + bc[0][3];
        float ig = sigm(pi), fg = sigm(pf), gg = tanhf_(pg), og = sigm(po);
        cs0 = fg * cs0 + ig * gg;
        const float h0 = og * tanhf_(cs0);

        // unit uu+16
        pi = gB.x + wih[1][0] * xc + bc[1][0];
        pf = gB.y + wih[1][1] * xc + bc[1][1];
        pg = gB.z + wih[1][2] * xc + bc[1][2];
        po = gB.w + wih[1][3] * xc + bc[1][3];
        ig = sigm(pi); fg = sigm(pf); gg = tanhf_(pg); og = sigm(po);
        cs1 = fg * cs1 + ig * gg;
        const float h1 = og * tanhf_(cs1);

        // producer-side hi/lo split; units (uu, uu+16) -> positions (2uu, 2uu+1)
        const short h0h = f2bf(h0);
        const short h0l = f2bf(h0 - bf2f(h0h));
        const short h1h = f2bf(h1);
        const short h1l = f2bf(h1 - bf2f(h1h));
        *(int*)&hhbuf[bb * HSTRIDE + 2 * uu] =
            (int)(unsigned short)h0h | ((int)(unsigned short)h1h << 16);
        *(int*)&hlbuf[bb * HSTRIDE + 2 * uu] =
            (int)(unsigned short)h0l | ((int)(unsigned short)h1l << 16);
        __syncthreads();
    }

    // ---- head: out[b] = h_T @ W_fc^T + b_fc ----
    if (tid < 16) {
        float s = b_fc[0];
        #pragma unroll
        for (int p = 0; p < 32; ++p) {
            const float hv = bf2f(hhbuf[tid * HSTRIDE + p]) +
                             bf2f(hlbuf[tid * HSTRIDE + p]);
            s += hv * W_fc[unit_of_pos(p)];
        }
        out[base + tid] = s;
    }
}

extern "C" void kernel_launch(void* const* d_in, const int* in_sizes, int n_in,
                              void* d_out, int out_size, void* d_ws, size_t ws_size,
                              hipStream_t stream) {
    const float* x    = (const float*)d_in[0];
    const float* W_ih = (const float*)d_in[1];
    const float* W_hh = (const float*)d_in[2];
    const float* b_ih = (const float*)d_in[3];
    const float* b_hh = (const float*)d_in[4];
    const float* W_fc = (const float*)d_in[5];
    const float* b_fc = (const float*)d_in[6];
    float* out = (float*)d_out;

    const int B = 8192;
    lstm_kernel<<<B / 16, 256, 0, stream>>>(x, W_ih, W_hh, b_ih, b_hh,
                                            W_fc, b_fc, out);
}

// Round 3
// 342.580 us; speedup vs baseline: 1.8363x; 1.0835x over previous
//
#include <hip/hip_runtime.h>
#include <hip/hip_bf16.h>

// LSTM: B=8192, T=512, H=32.
// Block = 256 threads (4 waves) per 16-batch group; 512 blocks.
// Wave w computes gate w via mfma_f32_16x16x32_bf16 with hi/lo bf16 split
// (3 chained MFMAs per n-tile). Gates exchanged through per-gate LDS planes
// (row stride 36 floats -> all accesses <=2-way bank aliasing = free).
// x staged through LDS in 64-step tiles (coalesced float4 loads) to kill the
// 2KB-stride L1-set thrash seen in round 2 (8.3 GB HBM refetch).
// Elementwise cell update: 2 units/thread, c-state in fp32 registers.

#define TT 512
#define HH 32

typedef short bf16x8 __attribute__((ext_vector_type(8)));
typedef float f32x4 __attribute__((ext_vector_type(4)));

__device__ __forceinline__ short f2bf(float f) {
    unsigned u = __float_as_uint(f);
    u = (u + 0x7FFFu + ((u >> 16) & 1u)) >> 16;
    return (short)u;
}
__device__ __forceinline__ float bf2f(short s) {
    return __uint_as_float(((unsigned)(unsigned short)s) << 16);
}
__device__ __forceinline__ float fastrcp(float x) { return __builtin_amdgcn_rcpf(x); }
__device__ __forceinline__ float sigm(float x) {
    return fastrcp(1.f + __expf(-x));
}
__device__ __forceinline__ float tanhf_(float x) {
    float e = __expf(2.f * x);            // e->inf => 1 ; e->0 => -1
    return 1.f - 2.f * fastrcp(e + 1.f);
}

// k-position permutation (applied identically to A and B fragments):
// p even -> unit p/2 ; p odd -> unit 16 + p/2. Producer thread's two h
// outputs (units u, u+16) form a contiguous pair at positions 2u, 2u+1.
__device__ __forceinline__ int unit_of_pos(int p) {
    return (p & 1) ? (16 + (p >> 1)) : (p >> 1);
}

#define GROW   36              // gate plane row stride (floats): 36 ≡ 4 mod 32
#define GPLANE (16 * GROW)     // 576 floats per gate plane
#define HSTRIDE 40             // h buf batch stride (shorts): 80B rows, 16B aligned
#define XROW   68              // x tile row stride (floats): 68 ≡ 4 mod 32

__launch_bounds__(256, 2)
__global__ void lstm_kernel(const float* __restrict__ x,
                            const float* __restrict__ W_ih,
                            const float* __restrict__ W_hh,
                            const float* __restrict__ b_ih,
                            const float* __restrict__ b_hh,
                            const float* __restrict__ W_fc,
                            const float* __restrict__ b_fc,
                            float* __restrict__ out) {
    __shared__ float gbuf[4 * GPLANE];     // [gate][batch][unit]
    __shared__ short hhbuf[16 * HSTRIDE];  // h hi-bf16, [batch][pos]
    __shared__ short hlbuf[16 * HSTRIDE];  // h lo-bf16
    __shared__ float xbuf[16 * XROW];      // x tile: [batch][t mod 64]

    const int tid  = threadIdx.x;
    const int lane = tid & 63;
    const int w    = tid >> 6;        // wave id == gate id (0:i 1:f 2:g 3:o)
    const int c    = lane & 15;       // MFMA m/n index
    const int q    = lane >> 4;       // quad
    const int k0   = q * 8;           // k-block base
    const int base = blockIdx.x * 16;

    // ---- MFMA weights: gate rows 32w + 16*ui + c, hi/lo bf16 split ----
    bf16x8 wh[2], wl[2];
    #pragma unroll
    for (int ui = 0; ui < 2; ++ui) {
        const int g = 32 * w + 16 * ui + c;
        #pragma unroll
        for (int j = 0; j < 8; ++j) {
            const int u = unit_of_pos(k0 + j);
            const float wf = W_hh[g * HH + u];
            const short hi = f2bf(wf);
            wh[ui][j] = hi;
            wl[ui][j] = f2bf(wf - bf2f(hi));
        }
    }

    // ---- elementwise constants: thread (bb, uu) updates units uu, uu+16 ----
    const int bb = tid & 15;
    const int uu = (tid >> 4) & 15;
    float wih[2][4], bc[2][4];
    #pragma unroll
    for (int ui = 0; ui < 2; ++ui) {
        #pragma unroll
        for (int g = 0; g < 4; ++g) {
            const int row = g * 32 + uu + 16 * ui;
            wih[ui][g] = W_ih[row];
            bc[ui][g]  = b_ih[row] + b_hh[row];
        }
    }

    // ---- init h = 0 ----
    for (int i = tid; i < 16 * HSTRIDE; i += 256) { hhbuf[i] = 0; hlbuf[i] = 0; }

    float cs0 = 0.f, cs1 = 0.f;       // c-state for units uu, uu+16 of batch bb

    // x-tile load indices: thread tid loads row (tid>>4), floats (tid&15)*4..+3
    const int xrow = tid >> 4;
    const int xj4  = (tid & 15) * 4;

    __syncthreads();

    for (int t = 0; t < TT; ++t) {
        // ---- x tile staging every 64 steps (coalesced float4) ----
        if ((t & 63) == 0) {
            const float4 v = *(const float4*)&x[(base + xrow) * TT + t + xj4];
            *(float4*)&xbuf[xrow * XROW + xj4] = v;
        }

        // ---- phase A: recurrent matvec (all 4 waves, own gate) ----
        const bf16x8 ahh = *(const bf16x8*)&hhbuf[c * HSTRIDE + k0];
        const bf16x8 ahl = *(const bf16x8*)&hlbuf[c * HSTRIDE + k0];

        #pragma unroll
        for (int ui = 0; ui < 2; ++ui) {
            f32x4 zz = {0.f, 0.f, 0.f, 0.f};
            zz = __builtin_amdgcn_mfma_f32_16x16x32_bf16(ahh, wh[ui], zz, 0, 0, 0);
            zz = __builtin_amdgcn_mfma_f32_16x16x32_bf16(ahl, wh[ui], zz, 0, 0, 0);
            zz = __builtin_amdgcn_mfma_f32_16x16x32_bf16(ahh, wl[ui], zz, 0, 0, 0);
            // lane (c,q) reg r: gate w, batch q*4+r, unit c+16ui
            #pragma unroll
            for (int r = 0; r < 4; ++r) {
                gbuf[w * GPLANE + (q * 4 + r) * GROW + c + 16 * ui] = zz[r];
            }
        }
        __syncthreads();

        // ---- phase B: elementwise cell update (2 units per thread) ----
        const int gb = bb * GROW + uu;
        const float gi0 = gbuf[0 * GPLANE + gb];
        const float gi1 = gbuf[0 * GPLANE + gb + 16];
        const float gf0 = gbuf[1 * GPLANE + gb];
        const float gf1 = gbuf[1 * GPLANE + gb + 16];
        const float gg0 = gbuf[2 * GPLANE + gb];
        const float gg1 = gbuf[2 * GPLANE + gb + 16];
        const float go0 = gbuf[3 * GPLANE + gb];
        const float go1 = gbuf[3 * GPLANE + gb + 16];

        const float xc = xbuf[bb * XROW + (t & 63)];

        // unit uu
        float pi = gi0 + wih[0][0] * xc + bc[0][0];
        float pf = gf0 + wih[0][1] * xc + bc[0][1];
        float pg = gg0 + wih[0][2] * xc + bc[0][2];
        float po = go0 + wih[0][3] * xc + bc[0][3];
        float ig = sigm(pi), fg = sigm(pf), gv = tanhf_(pg), og = sigm(po);
        cs0 = fg * cs0 + ig * gv;
        const float h0 = og * tanhf_(cs0);

        // unit uu+16
        pi = gi1 + wih[1][0] * xc + bc[1][0];
        pf = gf1 + wih[1][1] * xc + bc[1][1];
        pg = gg1 + wih[1][2] * xc + bc[1][2];
        po = go1 + wih[1][3] * xc + bc[1][3];
        ig = sigm(pi); fg = sigm(pf); gv = tanhf_(pg); og = sigm(po);
        cs1 = fg * cs1 + ig * gv;
        const float h1 = og * tanhf_(cs1);

        // packed hi/lo bf16 split; units (uu, uu+16) -> positions (2uu, 2uu+1)
        union { __hip_bfloat162 b; int i; } ph, pl;
        ph.b = __float22bfloat162_rn(make_float2(h0, h1));
        const float h0h = bf2f((short)(ph.i & 0xFFFF));
        const float h1h = bf2f((short)((unsigned)ph.i >> 16));
        pl.b = __float22bfloat162_rn(make_float2(h0 - h0h, h1 - h1h));

        *(int*)&hhbuf[bb * HSTRIDE + 2 * uu] = ph.i;
        *(int*)&hlbuf[bb * HSTRIDE + 2 * uu] = pl.i;
        __syncthreads();
    }

    // ---- head: out[b] = h_T @ W_fc^T + b_fc ----
    if (tid < 16) {
        float s = b_fc[0];
        #pragma unroll
        for (int p = 0; p < 32; ++p) {
            const float hv = bf2f(hhbuf[tid * HSTRIDE + p]) +
                             bf2f(hlbuf[tid * HSTRIDE + p]);
            s += hv * W_fc[unit_of_pos(p)];
        }
        out[base + tid] = s;
    }
}

extern "C" void kernel_launch(void* const* d_in, const int* in_sizes, int n_in,
                              void* d_out, int out_size, void* d_ws, size_t ws_size,
                              hipStream_t stream) {
    const float* x    = (const float*)d_in[0];
    const float* W_ih = (const float*)d_in[1];
    const float* W_hh = (const float*)d_in[2];
    const float* b_ih = (const float*)d_in[3];
    const float* b_hh = (const float*)d_in[4];
    const float* W_fc = (const float*)d_in[5];
    const float* b_fc = (const float*)d_in[6];
    float* out = (float*)d_out;

    const int B = 8192;
    lstm_kernel<<<B / 16, 256, 0, stream>>>(x, W_ih, W_hh, b_ih, b_hh,
                                            W_fc, b_fc, out);
}

// Round 4
// 326.912 us; speedup vs baseline: 1.9243x; 1.0479x over previous
//
#include <hip/hip_runtime.h>
#include <hip/hip_bf16.h>

// LSTM: B=8192, T=512, H=32.
// Block = 512 threads (8 waves) per 16-batch group; 512 blocks -> 16 waves/CU.
// Wave w computes MFMA n-tile w (gate rows 16w..16w+15) via
// mfma_f32_16x16x32_bf16 with hi/lo bf16 split (3 chained MFMAs).
// Weights/biases pre-scaled by -log2e (i,f,o) / +2log2e (g) so pre-activations
// are exp2-ready. Elementwise: 1 cell/thread, 4 exp2 + 3 rcp per cell using
//   i*g = (G-1)/((1+Ei)(G+1)),  o*tanh(c) = (C-1)/((C+1)(1+Eo)),  f = 1/(1+Ef)
// (exact identities). c-state in fp32 registers; h producer-split to bf16
// hi/lo in LDS (row stride 144B -> diagonal 16B-group map for b128 reads).

#define TT 512
#define HH 32
#define L2E 1.44269504088896340736f

typedef short bf16x8 __attribute__((ext_vector_type(8)));
typedef float f32x4 __attribute__((ext_vector_type(4)));

__device__ __forceinline__ short f2bf(float f) {
    unsigned u = __float_as_uint(f);
    u = (u + 0x7FFFu + ((u >> 16) & 1u)) >> 16;
    return (short)u;
}
__device__ __forceinline__ float bf2f(short s) {
    return __uint_as_float(((unsigned)(unsigned short)s) << 16);
}
__device__ __forceinline__ float fastrcp(float x) { return __builtin_amdgcn_rcpf(x); }
__device__ __forceinline__ float exp2f_(float x) { return __builtin_amdgcn_exp2f(x); }

// k-position permutation (applied identically to A and B fragments):
// p even -> unit p/2 ; p odd -> unit 16 + p/2.
__device__ __forceinline__ int unit_of_pos(int p) {
    return (p & 1) ? (16 + (p >> 1)) : (p >> 1);
}

#define GROW   36              // gbuf row stride (floats); 36 = 4 mod 32 -> 2-way
#define GPLANE (16 * GROW)     // 576 floats per n-tile plane
#define HSTRIDE 72             // h row stride (shorts): 144 B = 9*16 -> diagonal
#define XROW   132             // x tile row stride (floats): 132 = 4 mod 32

__launch_bounds__(512, 4)
__global__ void lstm_kernel(const float* __restrict__ x,
                            const float* __restrict__ W_ih,
                            const float* __restrict__ W_hh,
                            const float* __restrict__ b_ih,
                            const float* __restrict__ b_hh,
                            const float* __restrict__ W_fc,
                            const float* __restrict__ b_fc,
                            float* __restrict__ out) {
    __shared__ float gbuf[8 * GPLANE];     // [n-tile][batch][row-in-tile]
    __shared__ short hhbuf[16 * HSTRIDE];  // h hi-bf16, [batch][pos]
    __shared__ short hlbuf[16 * HSTRIDE];  // h lo-bf16
    __shared__ float xbuf[16 * XROW];      // x tile: [batch][t mod 128]

    const int tid  = threadIdx.x;
    const int lane = tid & 63;
    const int w    = tid >> 6;        // wave id == n-tile index (0..7)
    const int c    = lane & 15;       // MFMA m/n index
    const int q    = lane >> 4;       // quad
    const int k0   = q * 8;           // k-block base
    const int base = blockIdx.x * 16;

    // ---- MFMA B-fragment: gate row 16w + c, pre-scaled, hi/lo bf16 split ----
    // rows 0..31=i, 32..63=f, 64..95=g, 96..127=o. Scale: g -> +2*L2E, else -L2E.
    const int grow = 16 * w + c;
    const float wscale = ((grow >> 5) == 2) ? (2.0f * L2E) : (-L2E);
    bf16x8 wh, wl;
    #pragma unroll
    for (int j = 0; j < 8; ++j) {
        const int u = unit_of_pos(k0 + j);
        const float wf = W_hh[grow * HH + u] * wscale;
        const short hi = f2bf(wf);
        wh[j] = hi;
        wl[j] = f2bf(wf - bf2f(hi));
    }

    // ---- elementwise constants: thread (bb, uu) owns cell (batch bb, unit uu)
    const int bb = tid & 15;
    const int uu = tid >> 4;          // 0..31
    const int uhi = uu >> 4;          // which 16-unit half
    const int ulo = uu & 15;
    float wihs[4], bcs[4];
    #pragma unroll
    for (int g = 0; g < 4; ++g) {
        const int row = 32 * g + uu;
        const float sc = (g == 2) ? (2.0f * L2E) : (-L2E);
        wihs[g] = W_ih[row] * sc;
        bcs[g]  = (b_ih[row] + b_hh[row]) * sc;
    }

    // ---- init h = 0 ----
    for (int i = tid; i < 16 * HSTRIDE; i += 512) { hhbuf[i] = 0; hlbuf[i] = 0; }

    float cs = 0.f;                   // c-state for this thread's cell

    // x staging indices: 16 rows x 128 floats = 512 float4, one per thread
    const int xrow = tid >> 5;
    const int xj4  = (tid & 31) * 4;

    __syncthreads();

    for (int t = 0; t < TT; ++t) {
        // ---- stage x tile every 128 steps (coalesced float4) ----
        if ((t & 127) == 0) {
            const float4 v = *(const float4*)&x[(base + xrow) * TT + t + xj4];
            *(float4*)&xbuf[xrow * XROW + xj4] = v;
        }

        // ---- phase A: this wave's n-tile (3 chained MFMAs) ----
        const bf16x8 ahh = *(const bf16x8*)&hhbuf[c * HSTRIDE + k0];
        const bf16x8 ahl = *(const bf16x8*)&hlbuf[c * HSTRIDE + k0];
        f32x4 zz = {0.f, 0.f, 0.f, 0.f};
        zz = __builtin_amdgcn_mfma_f32_16x16x32_bf16(ahh, wh, zz, 0, 0, 0);
        zz = __builtin_amdgcn_mfma_f32_16x16x32_bf16(ahl, wh, zz, 0, 0, 0);
        zz = __builtin_amdgcn_mfma_f32_16x16x32_bf16(ahh, wl, zz, 0, 0, 0);
        // lane (c,q) reg r: batch q*4+r, gate row 16w+c
        #pragma unroll
        for (int r = 0; r < 4; ++r) {
            gbuf[w * GPLANE + (q * 4 + r) * GROW + c] = zz[r];
        }
        __syncthreads();

        // ---- phase B: cell update, 1 cell/thread ----
        // gate g lives in n-tile t8 = 2g + uhi at row-in-tile ulo
        const int gb = bb * GROW + ulo;
        const float gi = gbuf[(0 + uhi) * GPLANE + gb];
        const float gf = gbuf[(2 + uhi) * GPLANE + gb];
        const float gg = gbuf[(4 + uhi) * GPLANE + gb];
        const float go = gbuf[(6 + uhi) * GPLANE + gb];

        const float xc = xbuf[bb * XROW + (t & 127)];

        const float yi = gi + (wihs[0] * xc + bcs[0]);  // = -pi*log2e
        const float yf = gf + (wihs[1] * xc + bcs[1]);  // = -pf*log2e
        const float yg = gg + (wihs[2] * xc + bcs[2]);  // = 2*pg*log2e
        const float yo = go + (wihs[3] * xc + bcs[3]);  // = -po*log2e

        const float Ei = exp2f_(yi);
        const float Ef = exp2f_(yf);
        const float G  = exp2f_(yg);
        const float Eo = exp2f_(yo);

        const float fg  = fastrcp(1.f + Ef);                       // sigma(pf)
        const float igg = (G - 1.f) * fastrcp((1.f + Ei) * (G + 1.f)); // i*g
        const float cn  = fg * cs + igg;
        cs = cn;

        float yc = cn * (2.0f * L2E);
        yc = fminf(60.f, fmaxf(-60.f, yc));
        const float C = exp2f_(yc);
        const float h = (C - 1.f) * fastrcp((C + 1.f) * (1.f + Eo)); // o*tanh(c)

        // producer-side hi/lo bf16 split; unit uu -> position 2*ulo + uhi
        const short hh16 = f2bf(h);
        const short hl16 = f2bf(h - bf2f(hh16));
        const int pos = 2 * ulo + uhi;
        hhbuf[bb * HSTRIDE + pos] = hh16;
        hlbuf[bb * HSTRIDE + pos] = hl16;
        __syncthreads();
    }

    // ---- head: out[b] = h_T @ W_fc^T + b_fc ----
    if (tid < 16) {
        float s = b_fc[0];
        #pragma unroll
        for (int p = 0; p < 32; ++p) {
            const float hv = bf2f(hhbuf[tid * HSTRIDE + p]) +
                             bf2f(hlbuf[tid * HSTRIDE + p]);
            s += hv * W_fc[unit_of_pos(p)];
        }
        out[base + tid] = s;
    }
}

extern "C" void kernel_launch(void* const* d_in, const int* in_sizes, int n_in,
                              void* d_out, int out_size, void* d_ws, size_t ws_size,
                              hipStream_t stream) {
    const float* x    = (const float*)d_in[0];
    const float* W_ih = (const float*)d_in[1];
    const float* W_hh = (const float*)d_in[2];
    const float* b_ih = (const float*)d_in[3];
    const float* b_hh = (const float*)d_in[4];
    const float* W_fc = (const float*)d_in[5];
    const float* b_fc = (const float*)d_in[6];
    float* out = (float*)d_out;

    const int B = 8192;
    lstm_kernel<<<B / 16, 512, 0, stream>>>(x, W_ih, W_hh, b_ih, b_hh,
                                            W_fc, b_fc, out);
}

// Round 5
// 291.910 us; speedup vs baseline: 2.1551x; 1.1199x over previous
//
#include <hip/hip_runtime.h>

// LSTM: B=8192, T=512, H=32. Block = 512 threads (8 waves) per 16-batch group.
// TRANSPOSED MFMA: D = W'*h (A = weight rows, B = h columns=batches), with
// wave w's A-row m = 4*q^ + r chosen as (gate r, unit 4w+q^). The C/D layout
// (row=(lane>>4)*4+reg, col=lane&15) then delivers ALL FOUR gate pre-acts of
// cell (unit 4w+q, batch c) into one lane's 4 acc regs -> no gate exchange,
// no gbuf, ONE barrier/step (h ping-pong buffers). x-term + bias ride the
// MFMA C-initializer. hi/lo bf16 split (3 chained MFMAs) for fp32 accuracy.
// Gates pre-scaled by -log2e (i,f,o) / +2log2e (g); cell = 4 exp2 + 3 rcp.

#define TT 512
#define HH 32
#define L2E 1.44269504088896340736f

typedef short bf16x8 __attribute__((ext_vector_type(8)));
typedef float f32x4 __attribute__((ext_vector_type(4)));

__device__ __forceinline__ short f2bf(float f) {
    unsigned u = __float_as_uint(f);
    u = (u + 0x7FFFu + ((u >> 16) & 1u)) >> 16;
    return (short)u;
}
__device__ __forceinline__ float bf2f(short s) {
    return __uint_as_float(((unsigned)(unsigned short)s) << 16);
}
__device__ __forceinline__ float fastrcp(float x) { return __builtin_amdgcn_rcpf(x); }
__device__ __forceinline__ float exp2f_(float x) { return __builtin_amdgcn_exp2f(x); }

// k-position permutation (applied identically to A and B k-indexing):
// p even -> unit p/2 ; p odd -> unit 16 + p/2.
__device__ __forceinline__ int unit_of_pos(int p) {
    return (p & 1) ? (16 + (p >> 1)) : (p >> 1);
}

#define HS   72    // h row stride in shorts (144 B): b128 reads conflict-free
#define XROW 132   // x tile row stride (floats): 132 ≡ 4 mod 32 -> 2-way max

__launch_bounds__(512, 4)
__global__ void lstm_kernel(const float* __restrict__ x,
                            const float* __restrict__ W_ih,
                            const float* __restrict__ W_hh,
                            const float* __restrict__ b_ih,
                            const float* __restrict__ b_hh,
                            const float* __restrict__ W_fc,
                            const float* __restrict__ b_fc,
                            float* __restrict__ out) {
    __shared__ short hh0[16 * HS], hl0[16 * HS];   // h hi/lo, parity 0
    __shared__ short hh1[16 * HS], hl1[16 * HS];   // h hi/lo, parity 1
    __shared__ float xbuf[16 * XROW];              // x tile: [batch][t mod 128]

    const int tid  = threadIdx.x;
    const int lane = tid & 63;
    const int w    = tid >> 6;        // wave id (0..7): owns units 4w..4w+3
    const int c    = lane & 15;       // n index = batch; also A m index
    const int q    = lane >> 4;       // quad
    const int k0   = q * 8;           // k-block base
    const int base = blockIdx.x * 16;

    // ---- A-fragment (weights): lane supplies A[m=c][k=k0+j].
    // Row m -> (gate m&3, unit 4w + (m>>2)); W_hh row = 32*gate + unit.
    const int arow = 32 * (c & 3) + 4 * w + (c >> 2);
    const float asc = ((c & 3) == 2) ? (2.0f * L2E) : (-L2E);
    bf16x8 wah, wal;
    #pragma unroll
    for (int j = 0; j < 8; ++j) {
        const float wf = W_hh[arow * HH + unit_of_pos(k0 + j)] * asc;
        const short hi = f2bf(wf);
        wah[j] = hi;
        wal[j] = f2bf(wf - bf2f(hi));
    }

    // ---- this lane's cell: (unit u = 4w+q, batch c) ----
    const int u = 4 * w + q;
    float wihs[4], bcs[4];
    #pragma unroll
    for (int r = 0; r < 4; ++r) {
        const float sc = (r == 2) ? (2.0f * L2E) : (-L2E);
        wihs[r] = W_ih[32 * r + u] * sc;
        bcs[r]  = (b_ih[32 * r + u] + b_hh[32 * r + u]) * sc;
    }
    // h write offset: batch-row c, unit u at position 2*(u&15) + (u>>4)
    const int hwoff = c * HS + 2 * (u & 15) + (u >> 4);
    const int hroff = c * HS + k0;    // B-fragment read offset

    // ---- init: zero parity-0 h buffers (h0 = 0) ----
    for (int i = tid; i < 16 * HS; i += 512) { hh0[i] = 0; hl0[i] = 0; }

    float cs = 0.f;

    // x staging: 16 rows x 128 floats = 512 float4, one per thread
    const int xrow = tid >> 5;
    const int xj4  = (tid & 31) * 4;

    __syncthreads();

    #define STEP(t, rh, rl, wh_, wl_)                                        \
    {                                                                        \
        const bf16x8 bh = *(const bf16x8*)&rh[hroff];                        \
        const bf16x8 bl = *(const bf16x8*)&rl[hroff];                        \
        const float xc = xbuf[c * XROW + ((t) & 127)];                       \
        f32x4 acc;                                                           \
        _Pragma("unroll")                                                    \
        for (int r = 0; r < 4; ++r) acc[r] = wihs[r] * xc + bcs[r];          \
        acc = __builtin_amdgcn_mfma_f32_16x16x32_bf16(wah, bh, acc, 0, 0, 0);\
        acc = __builtin_amdgcn_mfma_f32_16x16x32_bf16(wah, bl, acc, 0, 0, 0);\
        acc = __builtin_amdgcn_mfma_f32_16x16x32_bf16(wal, bh, acc, 0, 0, 0);\
        const float Ei = exp2f_(acc[0]);                                     \
        const float Ef = exp2f_(acc[1]);                                     \
        const float G  = exp2f_(acc[2]);                                     \
        const float Eo = exp2f_(acc[3]);                                     \
        const float fg  = fastrcp(1.f + Ef);                                 \
        const float igg = (G - 1.f) * fastrcp((1.f + Ei) * (G + 1.f));       \
        cs = fg * cs + igg;                                                  \
        float yc = cs * (2.0f * L2E);                                        \
        yc = fminf(60.f, fmaxf(-60.f, yc));                                  \
        const float C = exp2f_(yc);                                          \
        const float h = (C - 1.f) * fastrcp((C + 1.f) * (1.f + Eo));         \
        const short h16 = f2bf(h);                                           \
        wh_[hwoff] = h16;                                                    \
        wl_[hwoff] = f2bf(h - bf2f(h16));                                    \
        __syncthreads();                                                     \
    }

    for (int t = 0; t < TT; t += 2) {
        if ((t & 127) == 0) {
            const float4 v = *(const float4*)&x[(base + xrow) * TT + t + xj4];
            *(float4*)&xbuf[xrow * XROW + xj4] = v;
            __syncthreads();
        }
        STEP(t,     hh0, hl0, hh1, hl1);   // read parity 0, write parity 1
        STEP(t + 1, hh1, hl1, hh0, hl0);   // read parity 1, write parity 0
    }
    // T even -> final h lives in parity-0 buffers; loop ended with a barrier.

    // ---- head: out[b] = h_T @ W_fc^T + b_fc ----
    if (tid < 16) {
        float s = b_fc[0];
        #pragma unroll
        for (int p = 0; p < 32; ++p) {
            const float hv = bf2f(hh0[tid * HS + p]) + bf2f(hl0[tid * HS + p]);
            s += hv * W_fc[unit_of_pos(p)];
        }
        out[base + tid] = s;
    }
}

extern "C" void kernel_launch(void* const* d_in, const int* in_sizes, int n_in,
                              void* d_out, int out_size, void* d_ws, size_t ws_size,
                              hipStream_t stream) {
    const float* x    = (const float*)d_in[0];
    const float* W_ih = (const float*)d_in[1];
    const float* W_hh = (const float*)d_in[2];
    const float* b_ih = (const float*)d_in[3];
    const float* b_hh = (const float*)d_in[4];
    const float* W_fc = (const float*)d_in[5];
    const float* b_fc = (const float*)d_in[6];
    float* out = (float*)d_out;

    const int B = 8192;
    lstm_kernel<<<B / 16, 512, 0, stream>>>(x, W_ih, W_hh, b_ih, b_hh,
                                            W_fc, b_fc, out);
}